// Round 7
// baseline (1243.767 us; speedup 1.0000x reference)
//
#include <hip/hip_runtime.h>
#include <hip/hip_bf16.h>

// Problem constants (fixed by the reference)
#define NN   507904          // nodes = 8192*62
#define NE   4063232         // edges = NN*8
#define NG   8192            // graphs
#define NPG  62              // nodes per graph
#define NBLKM 992            // NN/512 (mlp/gmlp grid)

// Bucket sort parameters
#define NB    248            // buckets = NN/2048 (exact)
#define BRNG  2048           // nodes per bucket (bucket = dst>>11)
#define BCAP  17152          // bucket record capacity (mean 16384, +6 sigma)
#define PBCAP 31744          // padded csr capacity/bucket (8-aligned)
#define P3BLK 992            // NE/4096 (exact)
#define CSRSZ (NB * PBCAP)   // 7,872,512 ints

// ---------------------------------------------------------------- ws layout (4B units)
// HA/HB: bf16 feature arrays (NN rows x 64ch + 1 sentinel zero row).
#define HSZ       (NN * 32 + 32)             // one bf16 buffer incl sentinel
#define OFF_HA    0
#define OFF_HB    (OFF_HA + HSZ)             // aliased: RECS (8.5M u), T1 (NN*4 u)
#define OFF_CSR   (OFF_HB + HSZ)             // CSRSZ ints (padded CSR)
#define OFF_CNT   (OFF_CSR + CSRSZ)          // NN ints
#define OFF_OFFA  (OFF_CNT + NN)             // NN ints
#define OFF_BCUR  (OFF_OFFA + NN)            // 256 ints
#define OFF_PART  (OFF_BCUR + 256)           // NBLKM*128 floats
#define OFF_PS    (OFF_PART + NBLKM * 128)   // NG*64 floats (graph pool sums)
#define OFF_WT    (OFF_PS + NG * 64)         // fp32 W1a^T: 256 floats
#define OFF_WTB   (OFF_WT + 256)             // bf16 transposed weights (20480 bf16)
#define OFF_SS    (OFF_WTB + 10240)          // 3 x (scale[64], shift[64])
// total ~= 42.7M units ~= 171 MB

// bf16 weight offsets (ushort units)
#define WB_W1B 0
#define WB_W2A 4096
#define WB_W2B 8192
#define WB_W3A 12288
#define WB_W3B 16384

typedef __attribute__((ext_vector_type(8))) short short8;
typedef __attribute__((ext_vector_type(4))) float f32x4;
typedef unsigned short ushort_t;

__device__ __forceinline__ ushort_t f2bf_bits(float f) {
  union { float f; unsigned u; } x; x.f = f;
  unsigned r = x.u + 0x7FFF + ((x.u >> 16) & 1);
  return (ushort_t)(r >> 16);
}
__device__ __forceinline__ float bf2f1(ushort_t u) {
  union { unsigned i; float f; } x; x.i = ((unsigned)u) << 16;
  return x.f;
}

// ---------------------------------------------------------------- weight prep
__global__ __launch_bounds__(256) void prep_weights(
    const float* __restrict__ w1a, const float* __restrict__ w1b,
    const float* __restrict__ w2a, const float* __restrict__ w2b,
    const float* __restrict__ w3a, const float* __restrict__ w3b,
    float* __restrict__ wt, ushort_t* __restrict__ wtb) {
  int b = blockIdx.x, tid = threadIdx.x;
  if (b == 0) {
    if (tid < 256) {
      int k = tid >> 6, n = tid & 63;          // src [4][64]
      wt[n * 4 + k] = w1a[tid];
    }
  } else {
    const float* s; ushort_t* d;
    switch (b) {
      case 1: s = w1b; d = wtb + WB_W1B; break;
      case 2: s = w2a; d = wtb + WB_W2A; break;
      case 3: s = w2b; d = wtb + WB_W2B; break;
      case 4: s = w3a; d = wtb + WB_W3A; break;
      default: s = w3b; d = wtb + WB_W3B; break;
    }
    for (int i = tid; i < 4096; i += 256) {
      int k = i >> 6, n = i & 63;              // src [k][n]
      d[n * 64 + k] = f2bf_bits(s[i]);         // dst [n][k]
    }
  }
}

// ---------------------------------------------------------------- CSR build: phase 1
__global__ __launch_bounds__(256) void p3_bin(
    const int* __restrict__ src, const int* __restrict__ dst,
    int* __restrict__ bcur, uint2* __restrict__ recs) {
  __shared__ int histo[256];
  __shared__ int scan_s[256];
  __shared__ int base_s[256];
  __shared__ int cur_s[256];
  __shared__ uint2 buf[4096];
  const int tid = threadIdx.x;
  const int e0 = blockIdx.x * 4096;

  histo[tid] = 0;
  __syncthreads();

  int d_[16], s_[16];
#pragma unroll
  for (int k = 0; k < 16; ++k) {
    int e = e0 + k * 256 + tid;
    d_[k] = dst[e]; s_[k] = src[e];
    atomicAdd(&histo[d_[k] >> 11], 1);
  }
  __syncthreads();

  int v = histo[tid];
  scan_s[tid] = v; __syncthreads();
  for (int s = 1; s < 256; s <<= 1) {
    int add = (tid >= s) ? scan_s[tid - s] : 0;
    __syncthreads();
    scan_s[tid] += add;
    __syncthreads();
  }
  int excl = scan_s[tid] - v;
  if (tid < NB) base_s[tid] = atomicAdd(&bcur[tid], v);
  cur_s[tid] = excl;
  histo[tid] = excl;
  __syncthreads();

#pragma unroll
  for (int k = 0; k < 16; ++k) {
    int b = d_[k] >> 11;
    int p = atomicAdd(&cur_s[b], 1);
    uint2 r; r.x = (unsigned)d_[k]; r.y = (unsigned)s_[k];
    buf[p] = r;
  }
  __syncthreads();

  for (int i = tid; i < 4096; i += 256) {
    uint2 r = buf[i];
    int b = (int)(r.x >> 11);
    int g = base_s[b] + (i - histo[b]);
    if (g < BCAP) recs[(size_t)b * BCAP + g] = r;
  }
}

// ---------------------------------------------------------------- CSR build: phase 2
__global__ __launch_bounds__(1024) void p4_build(
    const uint2* __restrict__ recs, const int* __restrict__ bcur,
    int* __restrict__ csr, int* __restrict__ cnt, int* __restrict__ offa) {
  __shared__ int lcnt[2048];
  __shared__ int pscan[1024];
  __shared__ int sstart[2048];
  __shared__ int scur[2048];
  const int b = blockIdx.x, tid = threadIdx.x;
  int m = bcur[b]; if (m > BCAP) m = BCAP;
  const int cbase = b * PBCAP;
  const int nbase = b << 11;
  const uint2* rp = recs + (size_t)b * BCAP;

  lcnt[tid] = 0; lcnt[1024 + tid] = 0;
  __syncthreads();
  for (int i = tid; i < m; i += 1024)
    atomicAdd(&lcnt[rp[i].x & (BRNG - 1)], 1);
  __syncthreads();

  int a0 = lcnt[2 * tid], a1 = lcnt[2 * tid + 1];
  int p0 = (a0 + 7) & ~7, p1 = (a1 + 7) & ~7;
  int ps = p0 + p1;
  pscan[tid] = ps; __syncthreads();
  for (int s = 1; s < 1024; s <<= 1) {
    int add = (tid >= s) ? pscan[tid - s] : 0;
    __syncthreads();
    pscan[tid] += add;
    __syncthreads();
  }
  int e0 = pscan[tid] - ps;
  sstart[2 * tid] = e0;          scur[2 * tid] = e0;
  sstart[2 * tid + 1] = e0 + p0; scur[2 * tid + 1] = e0 + p0;
  __syncthreads();

  cnt[nbase + tid] = lcnt[tid];
  cnt[nbase + 1024 + tid] = lcnt[1024 + tid];
  offa[nbase + tid] = cbase + sstart[tid];
  offa[nbase + 1024 + tid] = cbase + sstart[1024 + tid];
  __syncthreads();

  for (int i = tid; i < m; i += 1024) {
    uint2 r = rp[i];
    int p = atomicAdd(&scur[r.x & (BRNG - 1)], 1);
    csr[cbase + p] = (int)r.y;
  }
  __syncthreads();

#pragma unroll
  for (int k = 0; k < 2; ++k) {
    int i = k * 1024 + tid;
    int st = sstart[i], d = lcnt[i], p = (d + 7) & ~7;
    for (int q = d; q < p; ++q) csr[cbase + st + q] = NN;   // sentinel
  }
}

// ---------------------------------------------------------------- gather L1 (C=4)
__global__ __launch_bounds__(256) void gather1(
    const float4* __restrict__ x, const int* __restrict__ csr,
    const int* __restrict__ offa, const int* __restrict__ cnt,
    float4* __restrict__ tout) {
  int n = blockIdx.x * 256 + threadIdx.x;
  float4 a = x[n];
  int off = offa[n], deg = cnt[n];
  const int* cp = csr + off;
  int j = 0;
  for (; j + 4 <= deg; j += 4) {
    int s0 = cp[j], s1 = cp[j + 1], s2 = cp[j + 2], s3 = cp[j + 3];
    float4 v0 = x[s0], v1 = x[s1], v2 = x[s2], v3 = x[s3];
    a.x += v0.x + v1.x + v2.x + v3.x;
    a.y += v0.y + v1.y + v2.y + v3.y;
    a.z += v0.z + v1.z + v2.z + v3.z;
    a.w += v0.w + v1.w + v2.w + v3.w;
  }
  for (; j < deg; ++j) {
    float4 v = x[cp[j]];
    a.x += v.x; a.y += v.y; a.z += v.z; a.w += v.w;
  }
  tout[n] = a;
}

// ---------------------------------------------------------------- MLP L1 (MFMA)
__global__ __launch_bounds__(256) void mlp1(
    const float4* __restrict__ tin,
    const float* __restrict__ WaTf, const float* __restrict__ ba,
    const ushort_t* __restrict__ WbTb, const float* __restrict__ bb,
    ushort_t* __restrict__ routb, float* __restrict__ part) {
  __shared__ __align__(16) ushort_t zt[4096];
  __shared__ float red[512];
  __shared__ float wa_l1[320];
  const int tid = threadIdx.x;
  const int wave = tid >> 6, lane = tid & 63;
  const int col = lane & 15, quad = lane >> 4;

  if (tid < 256) wa_l1[tid] = WaTf[tid];
  if (tid < 64) wa_l1[256 + tid] = ba[tid];
  __syncthreads();

  short8 bWb[2][4];
#pragma unroll
  for (int k0 = 0; k0 < 2; ++k0)
#pragma unroll
    for (int nt = 0; nt < 4; ++nt)
      bWb[k0][nt] = *(const short8*)(WbTb + (nt * 16 + col) * 64 + k0 * 32 + quad * 8);
  float bb_n[4];
#pragma unroll
  for (int nt = 0; nt < 4; ++nt) bb_n[nt] = bb[nt * 16 + col];

  const int wbase = wave * 1024;
  float scol[4] = {0, 0, 0, 0}, qcol[4] = {0, 0, 0, 0};

  for (int it = 0; it < 8; ++it) {
    const int tile = blockIdx.x * 512 + it * 64 + wave * 16;
    short8 az0, az1;
    float4 t4 = tin[tile + col];
#pragma unroll
    for (int k0 = 0; k0 < 2; ++k0) {
      short8 az;
#pragma unroll
      for (int j = 0; j < 8; ++j) {
        int o = k0 * 32 + quad * 8 + j;
        float z = wa_l1[256 + o];
        z = fmaf(t4.x, wa_l1[o * 4 + 0], z);
        z = fmaf(t4.y, wa_l1[o * 4 + 1], z);
        z = fmaf(t4.z, wa_l1[o * 4 + 2], z);
        z = fmaf(t4.w, wa_l1[o * 4 + 3], z);
        az[j] = (short)f2bf_bits(fmaxf(z, 0.0f));
      }
      if (k0 == 0) az0 = az; else az1 = az;
    }

    f32x4 acc2[4];
#pragma unroll
    for (int nt = 0; nt < 4; ++nt) acc2[nt] = (f32x4){0.f, 0.f, 0.f, 0.f};
#pragma unroll
    for (int nt = 0; nt < 4; ++nt) {
      acc2[nt] = __builtin_amdgcn_mfma_f32_16x16x32_bf16(az0, bWb[0][nt], acc2[nt], 0, 0, 0);
      acc2[nt] = __builtin_amdgcn_mfma_f32_16x16x32_bf16(az1, bWb[1][nt], acc2[nt], 0, 0, 0);
    }
#pragma unroll
    for (int nt = 0; nt < 4; ++nt) {
#pragma unroll
      for (int r = 0; r < 4; ++r) {
        int row = tile + quad * 4 + r;
        float v = fmaxf(acc2[nt][r] + bb_n[nt], 0.0f);
        routb[(size_t)row * 64 + nt * 16 + col] = f2bf_bits(v);
        scol[nt] += v; qcol[nt] += v * v;
      }
    }
  }
  (void)zt;

#pragma unroll
  for (int nt = 0; nt < 4; ++nt) {
    float s = scol[nt], q = qcol[nt];
    s += __shfl_xor(s, 16); s += __shfl_xor(s, 32);
    q += __shfl_xor(q, 16); q += __shfl_xor(q, 32);
    if (quad == 0) {
      red[wave * 128 + nt * 16 + col] = s;
      red[wave * 128 + 64 + nt * 16 + col] = q;
    }
  }
  __syncthreads();
  if (tid < 128)
    part[blockIdx.x * 128 + tid] =
        red[tid] + red[128 + tid] + red[256 + tid] + red[384 + tid];
}

// ---------------------------------------------------------------- fused gather+MLP (layers 2/3)
// 4 waves/block, each wave: gather its 16 rows (lane=channel, chunks of 8
// independent loads, sentinel-padded) -> wave-private swizzled LDS -> MFMA
// MLP. No __syncthreads in the main loop. POOL: accumulate per-graph sums
// instead of writing feature rows.
template <bool POOL>
__global__ __launch_bounds__(256) void gmlp(
    const ushort_t* __restrict__ h, const int* __restrict__ csr,
    const int* __restrict__ offa, const int* __restrict__ cnt,
    const float* __restrict__ ss,
    const ushort_t* __restrict__ WaTb, const float* __restrict__ ba,
    const ushort_t* __restrict__ WbTb, const float* __restrict__ bb,
    ushort_t* __restrict__ routb, float* __restrict__ psum,
    float* __restrict__ part) {
  __shared__ __align__(16) ushort_t tt[4096];   // 4 waves x 16x64, XOR-swizzled
  __shared__ __align__(16) ushort_t zt[4096];
  __shared__ float red[512];
  __shared__ float pool[768];                   // 12 graphs x 64 ch
  const int tid = threadIdx.x;
  const int wave = tid >> 6, lane = tid & 63;
  const int col = lane & 15, quad = lane >> 4;
  const int g0 = (blockIdx.x * 512) / NPG;

  if (POOL) {
    for (int i = tid; i < 768; i += 256) pool[i] = 0.f;
    __syncthreads();
  }

  short8 bWa[2][4], bWb[2][4];
#pragma unroll
  for (int k0 = 0; k0 < 2; ++k0)
#pragma unroll
    for (int nt = 0; nt < 4; ++nt) {
      bWa[k0][nt] = *(const short8*)(WaTb + (nt * 16 + col) * 64 + k0 * 32 + quad * 8);
      bWb[k0][nt] = *(const short8*)(WbTb + (nt * 16 + col) * 64 + k0 * 32 + quad * 8);
    }
  float ba_n[4], bb_n[4];
#pragma unroll
  for (int nt = 0; nt < 4; ++nt) {
    ba_n[nt] = ba[nt * 16 + col];
    bb_n[nt] = bb[nt * 16 + col];
  }
  const float sc_c = ss[lane], sf_c = ss[64 + lane];

  const int wtb = wave * 1024;
  float scol[4] = {0, 0, 0, 0}, qcol[4] = {0, 0, 0, 0};

  for (int it = 0; it < 8; ++it) {
    const int rbase = blockIdx.x * 512 + it * 64 + wave * 16;

    // ---- gather: 16 rows, lane = channel
    for (int m = 0; m < 16; ++m) {
      const int n = rbase + m;
      const int off = offa[n], deg = cnt[n];
      float acc = bf2f1(h[(size_t)n * 64 + lane]);
      const int pdeg = (deg + 7) & ~7;
      for (int j = 0; j < pdeg; j += 8) {
        const int* cp = csr + off + j;
        int s0 = cp[0], s1 = cp[1], s2 = cp[2], s3 = cp[3];
        int s4 = cp[4], s5 = cp[5], s6 = cp[6], s7 = cp[7];
        float v0 = bf2f1(h[(size_t)s0 * 64 + lane]);
        float v1 = bf2f1(h[(size_t)s1 * 64 + lane]);
        float v2 = bf2f1(h[(size_t)s2 * 64 + lane]);
        float v3 = bf2f1(h[(size_t)s3 * 64 + lane]);
        float v4 = bf2f1(h[(size_t)s4 * 64 + lane]);
        float v5 = bf2f1(h[(size_t)s5 * 64 + lane]);
        float v6 = bf2f1(h[(size_t)s6 * 64 + lane]);
        float v7 = bf2f1(h[(size_t)s7 * 64 + lane]);
        acc += ((v0 + v1) + (v2 + v3)) + ((v4 + v5) + (v6 + v7));
      }
      const float t = fmaf(sc_c, acc, (float)(deg + 1) * sf_c);
      tt[wtb + m * 64 + ((((lane >> 3) ^ (m & 7)) << 3) | (lane & 7))] = f2bf_bits(t);
    }

    // ---- MFMA (wave-private LDS; DS ops wave-ordered, no barrier)
    short8 a0 = *(const short8*)&tt[wtb + col * 64 + ((quad ^ (col & 7)) << 3)];
    short8 a1 = *(const short8*)&tt[wtb + col * 64 + (((4 + quad) ^ (col & 7)) << 3)];

    f32x4 acc1[4];
#pragma unroll
    for (int nt = 0; nt < 4; ++nt) acc1[nt] = (f32x4){0.f, 0.f, 0.f, 0.f};
#pragma unroll
    for (int nt = 0; nt < 4; ++nt) {
      acc1[nt] = __builtin_amdgcn_mfma_f32_16x16x32_bf16(a0, bWa[0][nt], acc1[nt], 0, 0, 0);
      acc1[nt] = __builtin_amdgcn_mfma_f32_16x16x32_bf16(a1, bWa[1][nt], acc1[nt], 0, 0, 0);
    }
#pragma unroll
    for (int nt = 0; nt < 4; ++nt) {
      int oblk = nt * 2 + (col >> 3);
#pragma unroll
      for (int r = 0; r < 4; ++r) {
        int row = quad * 4 + r;
        float z = fmaxf(acc1[nt][r] + ba_n[nt], 0.0f);
        zt[wtb + row * 64 + (((oblk ^ (row & 7)) << 3) | (col & 7))] = f2bf_bits(z);
      }
    }
    short8 az0 = *(const short8*)&zt[wtb + col * 64 + ((quad ^ (col & 7)) << 3)];
    short8 az1 = *(const short8*)&zt[wtb + col * 64 + (((4 + quad) ^ (col & 7)) << 3)];

    f32x4 acc2[4];
#pragma unroll
    for (int nt = 0; nt < 4; ++nt) acc2[nt] = (f32x4){0.f, 0.f, 0.f, 0.f};
#pragma unroll
    for (int nt = 0; nt < 4; ++nt) {
      acc2[nt] = __builtin_amdgcn_mfma_f32_16x16x32_bf16(az0, bWb[0][nt], acc2[nt], 0, 0, 0);
      acc2[nt] = __builtin_amdgcn_mfma_f32_16x16x32_bf16(az1, bWb[1][nt], acc2[nt], 0, 0, 0);
    }
#pragma unroll
    for (int nt = 0; nt < 4; ++nt) {
#pragma unroll
      for (int r = 0; r < 4; ++r) {
        int row = rbase + quad * 4 + r;
        float v = fmaxf(acc2[nt][r] + bb_n[nt], 0.0f);
        if (POOL) {
          atomicAdd(&pool[(row / NPG - g0) * 64 + nt * 16 + col], v);
        } else {
          routb[(size_t)row * 64 + nt * 16 + col] = f2bf_bits(v);
        }
        scol[nt] += v; qcol[nt] += v * v;
      }
    }
  }

#pragma unroll
  for (int nt = 0; nt < 4; ++nt) {
    float s = scol[nt], q = qcol[nt];
    s += __shfl_xor(s, 16); s += __shfl_xor(s, 32);
    q += __shfl_xor(q, 16); q += __shfl_xor(q, 32);
    if (quad == 0) {
      red[wave * 128 + nt * 16 + col] = s;
      red[wave * 128 + 64 + nt * 16 + col] = q;
    }
  }
  __syncthreads();
  if (tid < 128)
    part[blockIdx.x * 128 + tid] =
        red[tid] + red[128 + tid] + red[256 + tid] + red[384 + tid];

  if (POOL) {
    const int span = (blockIdx.x * 512 + 511) / NPG - g0 + 1;
    for (int i = tid; i < span * 64; i += 256) {
      unsafeAtomicAdd(&psum[(size_t)(g0 + (i >> 6)) * 64 + (i & 63)], pool[i]);
    }
  }
}

// ---------------------------------------------------------------- BN finalize
__global__ __launch_bounds__(1024) void finalize(
    const float* __restrict__ part, const float* __restrict__ gma,
    const float* __restrict__ bta, float* __restrict__ ss) {
  __shared__ double sh[1024];
  __shared__ double tot[128];
  int tid = threadIdx.x;
  int col = tid & 127, chunk = tid >> 7;
  double a = 0.0;
  for (int b = chunk; b < NBLKM; b += 8) a += (double)part[b * 128 + col];
  sh[tid] = a;
  __syncthreads();
  if (tid < 128) {
    double v = 0.0;
#pragma unroll
    for (int k = 0; k < 8; ++k) v += sh[k * 128 + tid];
    tot[tid] = v;
  }
  __syncthreads();
  if (tid < 64) {
    double mean = tot[tid] / (double)NN;
    double var = tot[64 + tid] / (double)NN - mean * mean;
    double sc = (double)gma[tid] / sqrt(var + 1e-5);
    ss[tid] = (float)sc;
    ss[64 + tid] = (float)((double)bta[tid] - mean * sc);
  }
}

// ---------------------------------------------------------------- final fc
__global__ __launch_bounds__(64) void fc_out(
    const float* __restrict__ psum, const float* __restrict__ ss,
    const float* __restrict__ wfc, const float* __restrict__ bfc,
    float* __restrict__ out) {
  int g = blockIdx.x, c = threadIdx.x;
  float S = psum[(size_t)g * 64 + c];
  float pooled = fmaf(ss[c], S, (float)NPG * ss[64 + c]);
#pragma unroll
  for (int j = 0; j < 3; ++j) {
    float v = pooled * wfc[c * 3 + j];
    for (int m = 32; m; m >>= 1) v += __shfl_xor(v, m);
    if (c == 0) out[g * 3 + j] = v + bfc[j];
  }
}

// ---------------------------------------------------------------- launch
extern "C" void kernel_launch(void* const* d_in, const int* in_sizes, int n_in,
                              void* d_out, int out_size, void* d_ws, size_t ws_size,
                              hipStream_t stream) {
  const float* x    = (const float*)d_in[0];
  const int*   srcE = (const int*)d_in[1];
  const int*   dstE = (const int*)d_in[2];
  const float* W1a = (const float*)d_in[4],  *b1a = (const float*)d_in[5];
  const float* W1b = (const float*)d_in[6],  *b1b = (const float*)d_in[7];
  const float* g1  = (const float*)d_in[8],  *be1 = (const float*)d_in[9];
  const float* W2a = (const float*)d_in[10], *b2a = (const float*)d_in[11];
  const float* W2b = (const float*)d_in[12], *b2b = (const float*)d_in[13];
  const float* g2  = (const float*)d_in[14], *be2 = (const float*)d_in[15];
  const float* W3a = (const float*)d_in[16], *b3a = (const float*)d_in[17];
  const float* W3b = (const float*)d_in[18], *b3b = (const float*)d_in[19];
  const float* g3  = (const float*)d_in[20], *be3 = (const float*)d_in[21];
  const float* Wfc = (const float*)d_in[22], *bfc = (const float*)d_in[23];

  float* ws = (float*)d_ws;
  ushort_t* HA     = (ushort_t*)(ws + OFF_HA);   // bf16 rows + sentinel
  ushort_t* HB     = (ushort_t*)(ws + OFF_HB);   // bf16 rows + sentinel
  uint2*    RECS   = (uint2*)(ws + OFF_HB);      // alias: dead before gmlp L2
  float*    T1     = ws + OFF_HB;                // alias: L1 t (dead before L2)
  int*      CSR    = (int*)(ws + OFF_CSR);
  int*      CNT    = (int*)(ws + OFF_CNT);
  int*      OFFA   = (int*)(ws + OFF_OFFA);
  int*      BCUR   = (int*)(ws + OFF_BCUR);
  float*    PART   = ws + OFF_PART;
  float*    PS     = ws + OFF_PS;
  float*    WT     = ws + OFF_WT;
  ushort_t* WTB    = (ushort_t*)(ws + OFF_WTB);
  float*    SS     = ws + OFF_SS;

  prep_weights<<<6, 256, 0, stream>>>(W1a, W1b, W2a, W2b, W3a, W3b, WT, WTB);

  hipMemsetAsync(BCUR, 0, 256 * sizeof(int), stream);
  hipMemsetAsync(HA + (size_t)NN * 64, 0, 128, stream);   // sentinel rows
  hipMemsetAsync(HB + (size_t)NN * 64, 0, 128, stream);
  hipMemsetAsync(PS, 0, (size_t)NG * 64 * sizeof(float), stream);

  // ---- CSR build (bucket sort, padded to 8 with sentinel NN)
  p3_bin<<<P3BLK, 256, 0, stream>>>(srcE, dstE, BCUR, RECS);
  p4_build<<<NB, 1024, 0, stream>>>(RECS, BCUR, CSR, CNT, OFFA);

  // ---- layer 1 (t in T1, output HA)
  gather1<<<NN / 256, 256, 0, stream>>>((const float4*)x, CSR, OFFA, CNT,
                                        (float4*)T1);
  mlp1<<<NBLKM, 256, 0, stream>>>((const float4*)T1, WT, b1a,
                                  WTB + WB_W1B, b1b, HA, PART);
  finalize<<<1, 1024, 0, stream>>>(PART, g1, be1, SS + 0);

  // ---- layer 2 (fused gather+MLP: HA -> HB)
  gmlp<false><<<NBLKM, 256, 0, stream>>>(HA, CSR, OFFA, CNT, SS + 0,
                                         WTB + WB_W2A, b2a, WTB + WB_W2B, b2b,
                                         HB, nullptr, PART);
  finalize<<<1, 1024, 0, stream>>>(PART, g2, be2, SS + 128);

  // ---- layer 3 (fused gather+MLP+pool: HB -> PS)
  gmlp<true><<<NBLKM, 256, 0, stream>>>(HB, CSR, OFFA, CNT, SS + 128,
                                        WTB + WB_W3A, b3a, WTB + WB_W3B, b3b,
                                        nullptr, PS, PART);
  finalize<<<1, 1024, 0, stream>>>(PART, g3, be3, SS + 256);

  // ---- classifier
  fc_out<<<NG, 64, 0, stream>>>(PS, SS + 256, Wfc, bfc, (float*)d_out);
}

// Round 8
// 996.509 us; speedup vs baseline: 1.2481x; 1.2481x over previous
//
#include <hip/hip_runtime.h>
#include <hip/hip_bf16.h>

// Problem constants (fixed by the reference)
#define NN   507904          // nodes = 8192*62
#define NE   4063232         // edges = NN*8
#define NG   8192            // graphs
#define NPG  62              // nodes per graph
#define NBLKM 992            // NN/512 (mlp grid)

// Bucket sort parameters
#define NB    248            // buckets = NN/2048 (exact)
#define BRNG  2048           // nodes per bucket (bucket = dst>>11)
#define BCAP  17152          // bucket record capacity (mean 16384, +6 sigma)
#define PBCAP 31744          // padded csr capacity/bucket (8-aligned)
#define P3BLK 992            // NE/4096 (exact)
#define CSRSZ (NB * PBCAP)   // 7,872,512 ints

// ---------------------------------------------------------------- ws layout (4B units)
// H: bf16 feature rows (NN x 64 + sentinel zero row). Written by mlp1 (L1 out),
//    read by gather L2; then REUSED for L2 out (dead by then), read by gather L3.
// T: bf16 gather output (NN x 64). Also aliases RECS (packed sort records) and
//    T1 (L1 fp32 t, NN x 4) - both dead before their successors.
#define HSZ       (NN * 32 + 32)
#define OFF_H     0
#define OFF_T     (OFF_H + HSZ)
#define OFF_CSR   (OFF_T + NN * 32)          // CSRSZ ints (padded CSR)
#define OFF_CNT   (OFF_CSR + CSRSZ)          // NN ints
#define OFF_OFFA  (OFF_CNT + NN)             // NN ints
#define OFF_BCUR  (OFF_OFFA + NN)            // 256 ints
#define OFF_PART  (OFF_BCUR + 256)           // NBLKM*128 floats
#define OFF_PS    (OFF_PART + NBLKM * 128)   // NG*64 floats (graph pool sums)
#define OFF_WT    (OFF_PS + NG * 64)         // fp32 W1a^T: 256 floats
#define OFF_WTB   (OFF_WT + 256)             // bf16 transposed weights (20480 bf16)
#define OFF_SS    (OFF_WTB + 10240)          // 3 x (scale[64], shift[64])
// total ~= 42.5M units ~= 170 MB

// bf16 weight offsets (ushort units)
#define WB_W1B 0
#define WB_W2A 4096
#define WB_W2B 8192
#define WB_W3A 12288
#define WB_W3B 16384

typedef __attribute__((ext_vector_type(8))) short short8;
typedef __attribute__((ext_vector_type(4))) float f32x4;
typedef unsigned short ushort_t;

__device__ __forceinline__ ushort_t f2bf_bits(float f) {
  union { float f; unsigned u; } x; x.f = f;
  unsigned r = x.u + 0x7FFF + ((x.u >> 16) & 1);
  return (ushort_t)(r >> 16);
}
__device__ __forceinline__ float bf_lo(unsigned u) {
  union { unsigned i; float f; } x; x.i = u << 16; return x.f;
}
__device__ __forceinline__ float bf_hi(unsigned u) {
  union { unsigned i; float f; } x; x.i = u & 0xFFFF0000u; return x.f;
}

// ---------------------------------------------------------------- weight prep
__global__ __launch_bounds__(256) void prep_weights(
    const float* __restrict__ w1a, const float* __restrict__ w1b,
    const float* __restrict__ w2a, const float* __restrict__ w2b,
    const float* __restrict__ w3a, const float* __restrict__ w3b,
    float* __restrict__ wt, ushort_t* __restrict__ wtb) {
  int b = blockIdx.x, tid = threadIdx.x;
  if (b == 0) {
    if (tid < 256) {
      int k = tid >> 6, n = tid & 63;          // src [4][64]
      wt[n * 4 + k] = w1a[tid];
    }
  } else {
    const float* s; ushort_t* d;
    switch (b) {
      case 1: s = w1b; d = wtb + WB_W1B; break;
      case 2: s = w2a; d = wtb + WB_W2A; break;
      case 3: s = w2b; d = wtb + WB_W2B; break;
      case 4: s = w3a; d = wtb + WB_W3A; break;
      default: s = w3b; d = wtb + WB_W3B; break;
    }
    for (int i = tid; i < 4096; i += 256) {
      int k = i >> 6, n = i & 63;              // src [k][n]
      d[n * 64 + k] = f2bf_bits(s[i]);         // dst [n][k]
    }
  }
}

// ---------------------------------------------------------------- CSR build: phase 1
// Packed record: (dst & 2047) << 19 | src  (src < 2^19). Halves record traffic.
__global__ __launch_bounds__(256) void p3_bin(
    const int* __restrict__ src, const int* __restrict__ dst,
    int* __restrict__ bcur, unsigned* __restrict__ recs) {
  __shared__ int histo[256];
  __shared__ int scan_s[256];
  __shared__ int base_s[256];
  __shared__ int cur_s[256];
  __shared__ unsigned buf[4096];               // 16 KB reorder buffer
  __shared__ unsigned short bkt[4096];
  const int tid = threadIdx.x;
  const int e0 = blockIdx.x * 4096;

  histo[tid] = 0;
  __syncthreads();

  int d_[16], s_[16];
#pragma unroll
  for (int k = 0; k < 16; ++k) {
    int e = e0 + k * 256 + tid;                // coalesced
    d_[k] = dst[e]; s_[k] = src[e];
    atomicAdd(&histo[d_[k] >> 11], 1);
  }
  __syncthreads();

  int v = histo[tid];
  scan_s[tid] = v; __syncthreads();
  for (int s = 1; s < 256; s <<= 1) {
    int add = (tid >= s) ? scan_s[tid - s] : 0;
    __syncthreads();
    scan_s[tid] += add;
    __syncthreads();
  }
  int excl = scan_s[tid] - v;
  if (tid < NB) base_s[tid] = atomicAdd(&bcur[tid], v);
  cur_s[tid] = excl;
  histo[tid] = excl;                           // keep exclusive scan
  __syncthreads();

#pragma unroll
  for (int k = 0; k < 16; ++k) {
    int b = d_[k] >> 11;
    int p = atomicAdd(&cur_s[b], 1);
    buf[p] = (((unsigned)d_[k] & 2047u) << 19) | (unsigned)s_[k];
    bkt[p] = (unsigned short)b;
  }
  __syncthreads();

  for (int i = tid; i < 4096; i += 256) {
    int b = bkt[i];
    int g = base_s[b] + (i - histo[b]);
    if (g < BCAP) recs[(size_t)b * BCAP + g] = buf[i];
  }
}

// ---------------------------------------------------------------- CSR build: phase 2
__global__ __launch_bounds__(1024) void p4_build(
    const unsigned* __restrict__ recs, const int* __restrict__ bcur,
    int* __restrict__ csr, int* __restrict__ cnt, int* __restrict__ offa) {
  __shared__ int lcnt[2048];
  __shared__ int pscan[1024];
  __shared__ int sstart[2048];
  __shared__ int scur[2048];
  const int b = blockIdx.x, tid = threadIdx.x;
  int m = bcur[b]; if (m > BCAP) m = BCAP;
  const int cbase = b * PBCAP;
  const int nbase = b << 11;
  const unsigned* rp = recs + (size_t)b * BCAP;

  lcnt[tid] = 0; lcnt[1024 + tid] = 0;
  __syncthreads();
  for (int i = tid; i < m; i += 1024)
    atomicAdd(&lcnt[rp[i] >> 19], 1);
  __syncthreads();

  int a0 = lcnt[2 * tid], a1 = lcnt[2 * tid + 1];
  int p0 = (a0 + 7) & ~7, p1 = (a1 + 7) & ~7;
  int ps = p0 + p1;
  pscan[tid] = ps; __syncthreads();
  for (int s = 1; s < 1024; s <<= 1) {
    int add = (tid >= s) ? pscan[tid - s] : 0;
    __syncthreads();
    pscan[tid] += add;
    __syncthreads();
  }
  int e0 = pscan[tid] - ps;
  sstart[2 * tid] = e0;          scur[2 * tid] = e0;
  sstart[2 * tid + 1] = e0 + p0; scur[2 * tid + 1] = e0 + p0;
  __syncthreads();

  cnt[nbase + tid] = lcnt[tid];
  cnt[nbase + 1024 + tid] = lcnt[1024 + tid];
  offa[nbase + tid] = cbase + sstart[tid];
  offa[nbase + 1024 + tid] = cbase + sstart[1024 + tid];
  __syncthreads();

  for (int i = tid; i < m; i += 1024) {
    unsigned r = rp[i];
    int p = atomicAdd(&scur[r >> 19], 1);
    csr[cbase + p] = (int)(r & 0x7FFFFu);
  }
  __syncthreads();

#pragma unroll
  for (int k = 0; k < 2; ++k) {
    int i = k * 1024 + tid;
    int st = sstart[i], d = lcnt[i], p = (d + 7) & ~7;
    for (int q = d; q < p; ++q) csr[cbase + st + q] = NN;   // sentinel
  }
}

// ---------------------------------------------------------------- gather L1 (C=4)
__global__ __launch_bounds__(256) void gather1(
    const float4* __restrict__ x, const int* __restrict__ csr,
    const int* __restrict__ offa, const int* __restrict__ cnt,
    float4* __restrict__ tout) {
  int n = blockIdx.x * 256 + threadIdx.x;
  float4 a = x[n];
  int off = offa[n], deg = cnt[n];
  const int* cp = csr + off;
  int j = 0;
  for (; j + 4 <= deg; j += 4) {
    int s0 = cp[j], s1 = cp[j + 1], s2 = cp[j + 2], s3 = cp[j + 3];
    float4 v0 = x[s0], v1 = x[s1], v2 = x[s2], v3 = x[s3];
    a.x += v0.x + v1.x + v2.x + v3.x;
    a.y += v0.y + v1.y + v2.y + v3.y;
    a.z += v0.z + v1.z + v2.z + v3.z;
    a.w += v0.w + v1.w + v2.w + v3.w;
  }
  for (; j < deg; ++j) {
    float4 v = x[cp[j]];
    a.x += v.x; a.y += v.y; a.z += v.z; a.w += v.w;
  }
  tout[n] = a;
}

// ---------------------------------------------------------------- gather L2/3 (C=64, bf16 rows)
// Wave per node; 8-lane groups each load a padded-neighbor row as uint4
// (1 KB/wave-instruction); butterfly-sum; affine after sum.
__global__ __launch_bounds__(256) void gather64v2(
    const ushort_t* __restrict__ h, const int* __restrict__ csr,
    const int* __restrict__ offa, const int* __restrict__ cnt,
    const float* __restrict__ ss, ushort_t* __restrict__ tout) {
  const int lane = threadIdx.x & 63;
  const int n = blockIdx.x * 4 + (threadIdx.x >> 6);
  const int g = lane >> 3, sub = lane & 7;
  const int deg = cnt[n];
  const int off = offa[n];
  const int chunks = (deg + 7) >> 3;

  float acc[8] = {0.f, 0.f, 0.f, 0.f, 0.f, 0.f, 0.f, 0.f};
  for (int c = 0; c < chunks; ++c) {
    int row = csr[off + (c << 3) + g];
    uint4 u = *(const uint4*)(h + (size_t)row * 64 + (sub << 3));
    acc[0] += bf_lo(u.x); acc[1] += bf_hi(u.x);
    acc[2] += bf_lo(u.y); acc[3] += bf_hi(u.y);
    acc[4] += bf_lo(u.z); acc[5] += bf_hi(u.z);
    acc[6] += bf_lo(u.w); acc[7] += bf_hi(u.w);
  }
#pragma unroll
  for (int j = 0; j < 8; ++j) {
    acc[j] += __shfl_xor(acc[j], 8);
    acc[j] += __shfl_xor(acc[j], 16);
    acc[j] += __shfl_xor(acc[j], 32);
  }

  if (g == 0) {
    uint4 u = *(const uint4*)(h + (size_t)n * 64 + (sub << 3));
    acc[0] += bf_lo(u.x); acc[1] += bf_hi(u.x);
    acc[2] += bf_lo(u.y); acc[3] += bf_hi(u.y);
    acc[4] += bf_lo(u.z); acc[5] += bf_hi(u.z);
    acc[6] += bf_lo(u.w); acc[7] += bf_hi(u.w);
    const float m1 = (float)(deg + 1);
    const float4* scp = (const float4*)(ss + (sub << 3));
    const float4* sfp = (const float4*)(ss + 64 + (sub << 3));
    float4 sc0 = scp[0], sc1 = scp[1];
    float4 sf0 = sfp[0], sf1 = sfp[1];
    float t0 = fmaf(sc0.x, acc[0], m1 * sf0.x);
    float t1 = fmaf(sc0.y, acc[1], m1 * sf0.y);
    float t2 = fmaf(sc0.z, acc[2], m1 * sf0.z);
    float t3 = fmaf(sc0.w, acc[3], m1 * sf0.w);
    float t4 = fmaf(sc1.x, acc[4], m1 * sf1.x);
    float t5 = fmaf(sc1.y, acc[5], m1 * sf1.y);
    float t6 = fmaf(sc1.z, acc[6], m1 * sf1.z);
    float t7 = fmaf(sc1.w, acc[7], m1 * sf1.w);
    uint4 o;
    o.x = ((unsigned)f2bf_bits(t1) << 16) | f2bf_bits(t0);
    o.y = ((unsigned)f2bf_bits(t3) << 16) | f2bf_bits(t2);
    o.z = ((unsigned)f2bf_bits(t5) << 16) | f2bf_bits(t4);
    o.w = ((unsigned)f2bf_bits(t7) << 16) | f2bf_bits(t6);
    *(uint4*)(tout + (size_t)n * 64 + (sub << 3)) = o;
  }
}

// ---------------------------------------------------------------- MLP L1 (MFMA)
__global__ __launch_bounds__(256) void mlp1(
    const float4* __restrict__ tin,
    const float* __restrict__ WaTf, const float* __restrict__ ba,
    const ushort_t* __restrict__ WbTb, const float* __restrict__ bb,
    ushort_t* __restrict__ routb, float* __restrict__ part) {
  __shared__ float red[512];
  __shared__ float wa_l1[320];
  const int tid = threadIdx.x;
  const int wave = tid >> 6, lane = tid & 63;
  const int col = lane & 15, quad = lane >> 4;

  if (tid < 256) wa_l1[tid] = WaTf[tid];
  if (tid < 64) wa_l1[256 + tid] = ba[tid];
  __syncthreads();

  short8 bWb[2][4];
#pragma unroll
  for (int k0 = 0; k0 < 2; ++k0)
#pragma unroll
    for (int nt = 0; nt < 4; ++nt)
      bWb[k0][nt] = *(const short8*)(WbTb + (nt * 16 + col) * 64 + k0 * 32 + quad * 8);
  float bb_n[4];
#pragma unroll
  for (int nt = 0; nt < 4; ++nt) bb_n[nt] = bb[nt * 16 + col];

  float scol[4] = {0, 0, 0, 0}, qcol[4] = {0, 0, 0, 0};

  for (int it = 0; it < 8; ++it) {
    const int tile = blockIdx.x * 512 + it * 64 + wave * 16;
    short8 az0, az1;
    float4 t4 = tin[tile + col];
#pragma unroll
    for (int k0 = 0; k0 < 2; ++k0) {
      short8 az;
#pragma unroll
      for (int j = 0; j < 8; ++j) {
        int o = k0 * 32 + quad * 8 + j;
        float z = wa_l1[256 + o];
        z = fmaf(t4.x, wa_l1[o * 4 + 0], z);
        z = fmaf(t4.y, wa_l1[o * 4 + 1], z);
        z = fmaf(t4.z, wa_l1[o * 4 + 2], z);
        z = fmaf(t4.w, wa_l1[o * 4 + 3], z);
        az[j] = (short)f2bf_bits(fmaxf(z, 0.0f));
      }
      if (k0 == 0) az0 = az; else az1 = az;
    }

    f32x4 acc2[4];
#pragma unroll
    for (int nt = 0; nt < 4; ++nt) acc2[nt] = (f32x4){0.f, 0.f, 0.f, 0.f};
#pragma unroll
    for (int nt = 0; nt < 4; ++nt) {
      acc2[nt] = __builtin_amdgcn_mfma_f32_16x16x32_bf16(az0, bWb[0][nt], acc2[nt], 0, 0, 0);
      acc2[nt] = __builtin_amdgcn_mfma_f32_16x16x32_bf16(az1, bWb[1][nt], acc2[nt], 0, 0, 0);
    }
#pragma unroll
    for (int nt = 0; nt < 4; ++nt) {
#pragma unroll
      for (int r = 0; r < 4; ++r) {
        int row = tile + quad * 4 + r;
        float v = fmaxf(acc2[nt][r] + bb_n[nt], 0.0f);
        routb[(size_t)row * 64 + nt * 16 + col] = f2bf_bits(v);
        scol[nt] += v; qcol[nt] += v * v;
      }
    }
  }

#pragma unroll
  for (int nt = 0; nt < 4; ++nt) {
    float s = scol[nt], q = qcol[nt];
    s += __shfl_xor(s, 16); s += __shfl_xor(s, 32);
    q += __shfl_xor(q, 16); q += __shfl_xor(q, 32);
    if (quad == 0) {
      red[wave * 128 + nt * 16 + col] = s;
      red[wave * 128 + 64 + nt * 16 + col] = q;
    }
  }
  __syncthreads();
  if (tid < 128)
    part[blockIdx.x * 128 + tid] =
        red[tid] + red[128 + tid] + red[256 + tid] + red[384 + tid];
}

// ---------------------------------------------------------------- MLP L2/3 (MFMA)
// POOL: layer 3 - accumulate per-graph sums instead of writing feature rows.
template <bool POOL>
__global__ __launch_bounds__(256) void mlp2(
    const ushort_t* __restrict__ tin,
    const ushort_t* __restrict__ WaTb, const float* __restrict__ ba,
    const ushort_t* __restrict__ WbTb, const float* __restrict__ bb,
    ushort_t* __restrict__ routb, float* __restrict__ psum,
    float* __restrict__ part) {
  __shared__ __align__(16) ushort_t zt[4096];
  __shared__ float red[512];
  __shared__ float pool[768];                  // up to 12 graphs x 64 ch
  const int tid = threadIdx.x;
  const int wave = tid >> 6, lane = tid & 63;
  const int col = lane & 15, quad = lane >> 4;
  const int g0 = (blockIdx.x * 512) / NPG;

  if (POOL) {
    for (int i = tid; i < 768; i += 256) pool[i] = 0.f;
    __syncthreads();
  }

  short8 bWa[2][4], bWb[2][4];
#pragma unroll
  for (int k0 = 0; k0 < 2; ++k0)
#pragma unroll
    for (int nt = 0; nt < 4; ++nt) {
      bWa[k0][nt] = *(const short8*)(WaTb + (nt * 16 + col) * 64 + k0 * 32 + quad * 8);
      bWb[k0][nt] = *(const short8*)(WbTb + (nt * 16 + col) * 64 + k0 * 32 + quad * 8);
    }
  float ba_n[4], bb_n[4];
#pragma unroll
  for (int nt = 0; nt < 4; ++nt) {
    ba_n[nt] = ba[nt * 16 + col];
    bb_n[nt] = bb[nt * 16 + col];
  }

  const int wbase = wave * 1024;
  float scol[4] = {0, 0, 0, 0}, qcol[4] = {0, 0, 0, 0};

  for (int it = 0; it < 8; ++it) {
    const int tile = blockIdx.x * 512 + it * 64 + wave * 16;
    short8 a0 = *(const short8*)(tin + (size_t)(tile + col) * 64 + quad * 8);
    short8 a1 = *(const short8*)(tin + (size_t)(tile + col) * 64 + 32 + quad * 8);

    f32x4 acc1[4];
#pragma unroll
    for (int nt = 0; nt < 4; ++nt) acc1[nt] = (f32x4){0.f, 0.f, 0.f, 0.f};
#pragma unroll
    for (int nt = 0; nt < 4; ++nt) {
      acc1[nt] = __builtin_amdgcn_mfma_f32_16x16x32_bf16(a0, bWa[0][nt], acc1[nt], 0, 0, 0);
      acc1[nt] = __builtin_amdgcn_mfma_f32_16x16x32_bf16(a1, bWa[1][nt], acc1[nt], 0, 0, 0);
    }
#pragma unroll
    for (int nt = 0; nt < 4; ++nt) {
      int oblk = nt * 2 + (col >> 3);
#pragma unroll
      for (int r = 0; r < 4; ++r) {
        int row = quad * 4 + r;
        float z = fmaxf(acc1[nt][r] + ba_n[nt], 0.0f);
        zt[wbase + row * 64 + (((oblk ^ (row & 7)) << 3) | (col & 7))] = f2bf_bits(z);
      }
    }
    short8 az0 = *(const short8*)&zt[wbase + col * 64 + ((quad ^ (col & 7)) << 3)];
    short8 az1 = *(const short8*)&zt[wbase + col * 64 + (((4 + quad) ^ (col & 7)) << 3)];

    f32x4 acc2[4];
#pragma unroll
    for (int nt = 0; nt < 4; ++nt) acc2[nt] = (f32x4){0.f, 0.f, 0.f, 0.f};
#pragma unroll
    for (int nt = 0; nt < 4; ++nt) {
      acc2[nt] = __builtin_amdgcn_mfma_f32_16x16x32_bf16(az0, bWb[0][nt], acc2[nt], 0, 0, 0);
      acc2[nt] = __builtin_amdgcn_mfma_f32_16x16x32_bf16(az1, bWb[1][nt], acc2[nt], 0, 0, 0);
    }
#pragma unroll
    for (int nt = 0; nt < 4; ++nt) {
#pragma unroll
      for (int r = 0; r < 4; ++r) {
        int row = tile + quad * 4 + r;
        float v = fmaxf(acc2[nt][r] + bb_n[nt], 0.0f);
        if (POOL) {
          atomicAdd(&pool[(row / NPG - g0) * 64 + nt * 16 + col], v);
        } else {
          routb[(size_t)row * 64 + nt * 16 + col] = f2bf_bits(v);
        }
        scol[nt] += v; qcol[nt] += v * v;
      }
    }
  }

#pragma unroll
  for (int nt = 0; nt < 4; ++nt) {
    float s = scol[nt], q = qcol[nt];
    s += __shfl_xor(s, 16); s += __shfl_xor(s, 32);
    q += __shfl_xor(q, 16); q += __shfl_xor(q, 32);
    if (quad == 0) {
      red[wave * 128 + nt * 16 + col] = s;
      red[wave * 128 + 64 + nt * 16 + col] = q;
    }
  }
  __syncthreads();
  if (tid < 128)
    part[blockIdx.x * 128 + tid] =
        red[tid] + red[128 + tid] + red[256 + tid] + red[384 + tid];

  if (POOL) {
    const int span = (blockIdx.x * 512 + 511) / NPG - g0 + 1;
    for (int i = tid; i < span * 64; i += 256) {
      unsafeAtomicAdd(&psum[(size_t)(g0 + (i >> 6)) * 64 + (i & 63)], pool[i]);
    }
  }
}

// ---------------------------------------------------------------- BN finalize
__global__ __launch_bounds__(1024) void finalize(
    const float* __restrict__ part, const float* __restrict__ gma,
    const float* __restrict__ bta, float* __restrict__ ss) {
  __shared__ double sh[1024];
  __shared__ double tot[128];
  int tid = threadIdx.x;
  int col = tid & 127, chunk = tid >> 7;
  double a = 0.0;
  for (int b = chunk; b < NBLKM; b += 8) a += (double)part[b * 128 + col];
  sh[tid] = a;
  __syncthreads();
  if (tid < 128) {
    double v = 0.0;
#pragma unroll
    for (int k = 0; k < 8; ++k) v += sh[k * 128 + tid];
    tot[tid] = v;
  }
  __syncthreads();
  if (tid < 64) {
    double mean = tot[tid] / (double)NN;
    double var = tot[64 + tid] / (double)NN - mean * mean;
    double sc = (double)gma[tid] / sqrt(var + 1e-5);
    ss[tid] = (float)sc;
    ss[64 + tid] = (float)((double)bta[tid] - mean * sc);
  }
}

// ---------------------------------------------------------------- final fc
__global__ __launch_bounds__(64) void fc_out(
    const float* __restrict__ psum, const float* __restrict__ ss,
    const float* __restrict__ wfc, const float* __restrict__ bfc,
    float* __restrict__ out) {
  int g = blockIdx.x, c = threadIdx.x;
  float S = psum[(size_t)g * 64 + c];
  float pooled = fmaf(ss[c], S, (float)NPG * ss[64 + c]);
#pragma unroll
  for (int j = 0; j < 3; ++j) {
    float v = pooled * wfc[c * 3 + j];
    for (int m = 32; m; m >>= 1) v += __shfl_xor(v, m);
    if (c == 0) out[g * 3 + j] = v + bfc[j];
  }
}

// ---------------------------------------------------------------- launch
extern "C" void kernel_launch(void* const* d_in, const int* in_sizes, int n_in,
                              void* d_out, int out_size, void* d_ws, size_t ws_size,
                              hipStream_t stream) {
  const float* x    = (const float*)d_in[0];
  const int*   srcE = (const int*)d_in[1];
  const int*   dstE = (const int*)d_in[2];
  const float* W1a = (const float*)d_in[4],  *b1a = (const float*)d_in[5];
  const float* W1b = (const float*)d_in[6],  *b1b = (const float*)d_in[7];
  const float* g1  = (const float*)d_in[8],  *be1 = (const float*)d_in[9];
  const float* W2a = (const float*)d_in[10], *b2a = (const float*)d_in[11];
  const float* W2b = (const float*)d_in[12], *b2b = (const float*)d_in[13];
  const float* g2  = (const float*)d_in[14], *be2 = (const float*)d_in[15];
  const float* W3a = (const float*)d_in[16], *b3a = (const float*)d_in[17];
  const float* W3b = (const float*)d_in[18], *b3b = (const float*)d_in[19];
  const float* g3  = (const float*)d_in[20], *be3 = (const float*)d_in[21];
  const float* Wfc = (const float*)d_in[22], *bfc = (const float*)d_in[23];

  float* ws = (float*)d_ws;
  ushort_t* H      = (ushort_t*)(ws + OFF_H);    // bf16 rows + sentinel (L1 out, then L2 out)
  ushort_t* T      = (ushort_t*)(ws + OFF_T);    // bf16 gather output
  unsigned* RECS   = (unsigned*)(ws + OFF_T);    // alias: dead before gather1
  float*    T1     = ws + OFF_T;                 // alias: L1 fp32 t (dead before L2 gather)
  int*      CSR    = (int*)(ws + OFF_CSR);
  int*      CNT    = (int*)(ws + OFF_CNT);
  int*      OFFA   = (int*)(ws + OFF_OFFA);
  int*      BCUR   = (int*)(ws + OFF_BCUR);
  float*    PART   = ws + OFF_PART;
  float*    PS     = ws + OFF_PS;
  float*    WT     = ws + OFF_WT;
  ushort_t* WTB    = (ushort_t*)(ws + OFF_WTB);
  float*    SS     = ws + OFF_SS;

  prep_weights<<<6, 256, 0, stream>>>(W1a, W1b, W2a, W2b, W3a, W3b, WT, WTB);

  hipMemsetAsync(BCUR, 0, 256 * sizeof(int), stream);
  hipMemsetAsync(H + (size_t)NN * 64, 0, 128, stream);    // sentinel zero row
  hipMemsetAsync(PS, 0, (size_t)NG * 64 * sizeof(float), stream);

  // ---- CSR build (bucket sort, packed records, padded to 8 with sentinel NN)
  p3_bin<<<P3BLK, 256, 0, stream>>>(srcE, dstE, BCUR, RECS);
  p4_build<<<NB, 1024, 0, stream>>>(RECS, BCUR, CSR, CNT, OFFA);

  // ---- layer 1: gather(x) -> T1, MLP -> H
  gather1<<<NN / 256, 256, 0, stream>>>((const float4*)x, CSR, OFFA, CNT,
                                        (float4*)T1);
  mlp1<<<NBLKM, 256, 0, stream>>>((const float4*)T1, WT, b1a,
                                  WTB + WB_W1B, b1b, H, PART);
  finalize<<<1, 1024, 0, stream>>>(PART, g1, be1, SS + 0);

  // ---- layer 2: gather(H) -> T, MLP -> H (H dead after gather)
  gather64v2<<<NN / 4, 256, 0, stream>>>(H, CSR, OFFA, CNT, SS + 0, T);
  mlp2<false><<<NBLKM, 256, 0, stream>>>(T, WTB + WB_W2A, b2a,
                                         WTB + WB_W2B, b2b, H, nullptr, PART);
  finalize<<<1, 1024, 0, stream>>>(PART, g2, be2, SS + 128);

  // ---- layer 3: gather(H) -> T, MLP + pool -> PS
  gather64v2<<<NN / 4, 256, 0, stream>>>(H, CSR, OFFA, CNT, SS + 128, T);
  mlp2<true><<<NBLKM, 256, 0, stream>>>(T, WTB + WB_W3A, b3a,
                                        WTB + WB_W3B, b3b, nullptr, PS, PART);
  finalize<<<1, 1024, 0, stream>>>(PART, g3, be3, SS + 256);

  // ---- classifier
  fc_out<<<NG, 64, 0, stream>>>(PS, SS + 256, Wfc, bfc, (float*)d_out);
}